// Round 5
// baseline (609.640 us; speedup 1.0000x reference)
//
#include <hip/hip_runtime.h>

// CharRNN fused: B=256, L=1024, V=40, H=128. One block/CU, 512 thr = 8 waves.
// R5: 8-way k-split. Wave w OWNS h-slice S_w=[16w,16w+16) (lanes 0-15 hold it).
// Per step each wave computes partial dots over its 16-wide k-slice for ALL
// 128 j via v_readlane broadcasts; logits piggyback (lane v<40 holds
// Wo[v][S_w]). Cross-wave K-reduce: 8 conflict-free ds_read_b32 per lane.
// 2 waves/SIMD so reduce/tanh/barrier stalls of one wave are hidden by the
// other wave's k-loop issue. Weights = 48 floats/lane -> fits arch VGPRs
// (R3/R4's 96-float set was pushed to AGPRs; VGPR_Count=80 < need).
// x[] read via uniform s_load (no xbuf staging).

#define BB 256
#define LL 1024
#define VV 40
#define HH 128
#define WIN 16
#define NW 8      // waves per block
#define KS 16     // k-slice width per wave

__device__ __forceinline__ float fast_tanh(float x) {
    // tanh(x) = 1 - 2/(exp(2x)+1); overflow -> inf -> rcp -> 0 -> +1 (correct)
    float e = __expf(2.0f * x);
    float r = __builtin_amdgcn_rcpf(e + 1.0f);
    return 1.0f - 2.0f * r;
}

__device__ __forceinline__ float bcast(float v, int k) {
    return __int_as_float(__builtin_amdgcn_readlane(__float_as_int(v), k));
}

__global__ __launch_bounds__(512, 2) void rnn_fused(
    const int*   __restrict__ x,       // [B,L]
    const float* __restrict__ hidden,  // [B,H]
    const float* __restrict__ emb,     // [V,H]
    const float* __restrict__ Wh,      // [H,H]
    const float* __restrict__ Wo,      // [V,H]
    const float* __restrict__ b_h,     // [H]
    const float* __restrict__ b_y,     // [V]
    float*       __restrict__ out)     // [B*L*V logits][B*H final_hidden]
{
    __shared__ float emb_s[VV * HH];        // 20 KB (b_h folded in)
    __shared__ float part[2][NW][HH];       //  8 KB  main-dot partials (dbuf)
    __shared__ float lpart[WIN][NW][48];    // 24 KB  logit partials (pad 40->48)
    __shared__ float bys[VV];
    // ~52.2 KB static LDS

    const int tid  = threadIdx.x;
    const int b    = blockIdx.x;
    const int w    = tid >> 6;          // wave 0..7
    const int lane = tid & 63;
    const int kq   = w * KS;            // wave's k-slice base

    // ---- stage embedding(+b_h), b_y ----
    for (int i = tid; i < VV * HH; i += 512)
        emb_s[i] = emb[i] + b_h[i & (HH - 1)];
    if (tid < VV) bys[tid] = b_y[tid];

    // ---- weights into registers (48 floats/lane) ----
    // wreg0[k] = Wh[lane][kq+k], wreg1[k] = Wh[lane+64][kq+k],
    // woreg[k] = Wo[min(lane,39)][kq+k]
    float wreg0[KS], wreg1[KS], woreg[KS];
    {
        const float4* p0 = (const float4*)(Wh + (size_t)lane * HH + kq);
        const float4* p1 = (const float4*)(Wh + (size_t)(lane + 64) * HH + kq);
        int vrow = (lane < VV) ? lane : 0;
        const float4* p2 = (const float4*)(Wo + (size_t)vrow * HH + kq);
        #pragma unroll
        for (int i = 0; i < KS / 4; i++) {
            float4 a = p0[i], c = p1[i], d = p2[i];
            wreg0[4*i+0] = a.x; wreg0[4*i+1] = a.y; wreg0[4*i+2] = a.z; wreg0[4*i+3] = a.w;
            wreg1[4*i+0] = c.x; wreg1[4*i+1] = c.y; wreg1[4*i+2] = c.z; wreg1[4*i+3] = c.w;
            woreg[4*i+0] = d.x; woreg[4*i+1] = d.y; woreg[4*i+2] = d.z; woreg[4*i+3] = d.w;
        }
    }
    float hreg = 0.f;
    if (lane < KS) hreg = hidden[(size_t)b * HH + kq + lane];
    __syncthreads();

    int p = 0;
    const int* xrow = x + (size_t)b * LL;
    int idx_cur = xrow[0];              // uniform -> s_load

    for (int t = 0; t < LL; ++t) {
        // e for THIS step (lanes<16); k-loop hides the LDS latency
        float e_cur = 0.f;
        if (lane < KS) e_cur = emb_s[idx_cur * HH + kq + lane];
        int tn = t + 1; if (tn > LL - 1) tn = LL - 1;
        int idx_next = xrow[tn];        // uniform -> s_load, prefetch

        // ---- broadcast k-loop over my wave's 16-wide k-slice ----
        float acc0 = 0.f, acc1 = 0.f, lacc = 0.f;
        #pragma unroll
        for (int k = 0; k < KS; ++k) {
            float s = bcast(hreg, k);          // h_{t}[kq+k]
            acc0 = fmaf(s, wreg0[k], acc0);    // j = lane
            acc1 = fmaf(s, wreg1[k], acc1);    // j = lane+64
            lacc = fmaf(s, woreg[k], lacc);    // v = lane (<40)
        }

        part[p][w][lane]      = acc0;
        part[p][w][lane + 64] = acc1;
        if (t != 0 && lane < VV) lpart[(t - 1) & (WIN - 1)][w][lane] = lacc;
        __syncthreads();

        // ---- burst: reduce+store logit rows [t-16, t) ----
        if (t >= WIN && (t & (WIN - 1)) == 0) {
            const int rbase = t - WIN;
            #pragma unroll
            for (int q = 0; q < 2; ++q) {
                int o = tid + 512 * q;         // 0..1023, need < 640
                if (o < WIN * VV) {
                    int tp = o / VV;
                    int v  = o - VV * tp;
                    float sm = bys[v];
                    #pragma unroll
                    for (int ww = 0; ww < NW; ++ww) sm += lpart[tp][ww][v];
                    out[(size_t)b * LL * VV + (size_t)(rbase + tp) * VV + v] = sm;
                }
            }
            __syncthreads();   // next step's lpart[0] write must wait
        }

        // ---- K-reduction + tanh: my wave's 16-wide j-slice ----
        if (lane < KS) {
            int j = kq + lane;
            float vsum = part[p][0][j] + part[p][1][j]
                       + part[p][2][j] + part[p][3][j]
                       + part[p][4][j] + part[p][5][j]
                       + part[p][6][j] + part[p][7][j];
            hreg = fast_tanh(vsum + e_cur);
        }
        idx_cur = idx_next;
        p ^= 1;
    }

    // ---- epilogue: logits for row L-1 from final h, then last burst ----
    {
        float lacc = 0.f;
        #pragma unroll
        for (int k = 0; k < KS; ++k) {
            float s = bcast(hreg, k);
            lacc = fmaf(s, woreg[k], lacc);
        }
        if (lane < VV) lpart[(LL - 1) & (WIN - 1)][w][lane] = lacc;
        __syncthreads();
        const int rbase = LL - WIN;
        #pragma unroll
        for (int q = 0; q < 2; ++q) {
            int o = tid + 512 * q;
            if (o < WIN * VV) {
                int tp = o / VV;
                int v  = o - VV * tp;
                float sm = bys[v];
                #pragma unroll
                for (int ww = 0; ww < NW; ++ww) sm += lpart[tp][ww][v];
                out[(size_t)b * LL * VV + (size_t)(rbase + tp) * VV + v] = sm;
            }
        }
        // final hidden
        if (lane < KS)
            out[(size_t)BB * LL * VV + (size_t)b * HH + kq + lane] = hreg;
    }
}

extern "C" void kernel_launch(void* const* d_in, const int* in_sizes, int n_in,
                              void* d_out, int out_size, void* d_ws, size_t ws_size,
                              hipStream_t stream) {
    const int*   x      = (const int*)  d_in[0];
    const float* hidden = (const float*)d_in[1];
    const float* emb    = (const float*)d_in[2];
    const float* Wh     = (const float*)d_in[3];
    const float* Wo     = (const float*)d_in[4];
    const float* bh     = (const float*)d_in[5];
    const float* by     = (const float*)d_in[6];
    float*       out    = (float*)      d_out;

    rnn_fused<<<dim3(BB), dim3(512), 0, stream>>>(x, hidden, emb, Wh, Wo, bh, by, out);
}